// Round 1
// baseline (237.874 us; speedup 1.0000x reference)
//
#include <hip/hip_runtime.h>

// Unfold (im2col) for x[16, 64, 128, 128] fp32, K=3, PAD=1, STR=1, DIL=1.
// out[b, c*9 + k, oh*128 + ow] = x[b, c, oh + k/3 - 1, ow + k%3 - 1] (0 if OOB)
// out flat: [16, 576, 16384] = 150,994,944 floats.

#define C_DIM 64
#define H_DIM 128
#define W_DIM 128
// out_h = out_w = 128, L = 16384

__global__ __launch_bounds__(256) void unfold_f4_kernel(
    const float* __restrict__ x, float* __restrict__ out, int total4) {
    const int stride = gridDim.x * blockDim.x;
    for (int idx = blockIdx.x * blockDim.x + threadIdx.x; idx < total4;
         idx += stride) {
        // idx is in float4 units. Per output row (128 floats) -> 32 float4.
        int ow4  = idx & 31;          // which float4 within the row
        int rest = idx >> 5;
        int oh   = rest & 127;
        rest >>= 7;
        int k  = rest % 9;            // kernel flat index (fastest after L)
        int bc = rest / 9;            // b*64 + c, contiguous into x
        int i = k / 3;
        int j = k - 3 * i;
        int ih = oh + i - 1;

        float4 v = make_float4(0.f, 0.f, 0.f, 0.f);
        if (ih >= 0 && ih < H_DIM) {
            const float* row = x + ((long)bc * H_DIM + ih) * W_DIM;
            int iw0 = (ow4 << 2) + j - 1;   // range [-1, 128]
            // Border guards only actually fire for ow4==0 (j==0) and
            // ow4==31 (j==2); interior threads get 4 cached scalar loads.
            v.x = (iw0     >= 0 && iw0     < W_DIM) ? row[iw0]     : 0.f;
            v.y = (iw0 + 1 >= 0 && iw0 + 1 < W_DIM) ? row[iw0 + 1] : 0.f;
            v.z = (iw0 + 2 >= 0 && iw0 + 2 < W_DIM) ? row[iw0 + 2] : 0.f;
            v.w = (iw0 + 3 >= 0 && iw0 + 3 < W_DIM) ? row[iw0 + 3] : 0.f;
        }
        reinterpret_cast<float4*>(out)[idx] = v;  // coalesced 16B store
    }
}

extern "C" void kernel_launch(void* const* d_in, const int* in_sizes, int n_in,
                              void* d_out, int out_size, void* d_ws, size_t ws_size,
                              hipStream_t stream) {
    const float* x = (const float*)d_in[0];
    float* out = (float*)d_out;
    int total4 = out_size / 4;  // 37,748,736 float4 stores

    const int block = 256;
    const int grid = 2048;  // 256 CUs x 8 blocks, grid-stride covers the rest
    unfold_f4_kernel<<<grid, block, 0, stream>>>(x, out, total4);
}

// Round 2
// 152.096 us; speedup vs baseline: 1.5640x; 1.5640x over previous
//
#include <hip/hip_runtime.h>

// Unfold (im2col) x[16, 64, 128, 128] fp32, K=3, PAD=1, STR=1, DIL=1.
// out[bc*9 + k][oh*128 + ow] = x[bc][oh + k/3 - 1][ow + k%3 - 1]  (0 if OOB)
//
// One thread per (bc, oh, ow4) produces all 9 kernel offsets:
//   - 3 aligned float4 row loads (coalesced, full cache-line use)
//   - left/right halo via 32-wide lane shuffles (no unaligned loads)
//   - 9 coalesced float4 stores

#define H_DIM 128
#define W_DIM 128
#define PLANE (H_DIM * W_DIM)   // 16384 floats; also the out per-k plane size

__global__ __launch_bounds__(256) void unfold9_kernel(
    const float* __restrict__ x, float* __restrict__ out, int total) {
    const int stride = gridDim.x * blockDim.x;
    for (int t = blockIdx.x * blockDim.x + threadIdx.x; t < total; t += stride) {
        const int ow4 = t & 31;          // float4 index within a 128-wide row
        const int oh  = (t >> 5) & 127;
        const int bc  = t >> 12;         // b*64 + c

        const float* plane = x + (size_t)bc * PLANE;

        float4 a[3];
        float  lft[3], rgt[3];
#pragma unroll
        for (int i = 0; i < 3; ++i) {
            const int ih = oh + i - 1;
            float4 v = make_float4(0.f, 0.f, 0.f, 0.f);
            if (ih >= 0 && ih < H_DIM)
                v = reinterpret_cast<const float4*>(plane + ih * W_DIM)[ow4];
            a[i] = v;
            // halo from neighbor lanes; ow4 groups align with 32-lane segments
            const float l = __shfl_up(v.w, 1, 32);    // x[.., 4*ow4 - 1]
            const float r = __shfl_down(v.x, 1, 32);  // x[.., 4*ow4 + 4]
            lft[i] = (ow4 == 0)  ? 0.f : l;
            rgt[i] = (ow4 == 31) ? 0.f : r;
        }

        float* obase = out + (size_t)bc * (9 * PLANE) + (oh << 7) + (ow4 << 2);
#pragma unroll
        for (int i = 0; i < 3; ++i) {
            const float4 o0 = make_float4(lft[i], a[i].x, a[i].y, a[i].z); // j=0
            const float4 o1 = a[i];                                        // j=1
            const float4 o2 = make_float4(a[i].y, a[i].z, a[i].w, rgt[i]); // j=2
            *reinterpret_cast<float4*>(obase + (size_t)(3 * i + 0) * PLANE) = o0;
            *reinterpret_cast<float4*>(obase + (size_t)(3 * i + 1) * PLANE) = o1;
            *reinterpret_cast<float4*>(obase + (size_t)(3 * i + 2) * PLANE) = o2;
        }
    }
}

extern "C" void kernel_launch(void* const* d_in, const int* in_sizes, int n_in,
                              void* d_out, int out_size, void* d_ws, size_t ws_size,
                              hipStream_t stream) {
    const float* x = (const float*)d_in[0];
    float* out = (float*)d_out;

    // work items = BC * OH * OW4 = 1024 * 128 * 32 = 4,194,304
    const int total = (out_size / 9) / 4;
    const int block = 256;
    const int grid  = 2048;  // 8 blocks/CU; grid-stride covers 8 iterations
    unfold9_kernel<<<grid, block, 0, stream>>>(x, out, total);
}

// Round 3
// 108.722 us; speedup vs baseline: 2.1879x; 1.3989x over previous
//
#include <hip/hip_runtime.h>

// Unfold (im2col) x[16, 64, 128, 128] fp32, K=3, PAD=1, STR=1, DIL=1.
// out[bc*9 + k][oh*128 + ow] = x[bc][oh + k/3 - 1][ow + k%3 - 1]  (0 if OOB)
//
// One thread per (bc, oh, ow4) produces all 9 kernel offsets:
//   - 3 aligned float4 row loads (coalesced, cached — 3x L1 reuse)
//   - left/right halo via 32-wide lane shuffles
//   - 9 coalesced float4 NON-TEMPORAL stores (output is write-once; bypass
//     L2/L3 allocation so the 604 MB stream doesn't thrash the caches or
//     evict the L3-resident 64 MB input between graph replays)

#define H_DIM 128
#define W_DIM 128
#define PLANE (H_DIM * W_DIM)   // 16384 floats; also the out per-k plane size

typedef float f4 __attribute__((ext_vector_type(4)));

__global__ __launch_bounds__(256) void unfold9_nt_kernel(
    const float* __restrict__ x, float* __restrict__ out, int total) {
    const int stride = gridDim.x * blockDim.x;
    for (int t = blockIdx.x * blockDim.x + threadIdx.x; t < total; t += stride) {
        const int ow4 = t & 31;          // float4 index within a 128-wide row
        const int oh  = (t >> 5) & 127;
        const int bc  = t >> 12;         // b*64 + c

        const float* plane = x + (size_t)bc * PLANE;

        f4    a[3];
        float lft[3], rgt[3];
#pragma unroll
        for (int i = 0; i < 3; ++i) {
            const int ih = oh + i - 1;
            f4 v = {0.f, 0.f, 0.f, 0.f};
            if (ih >= 0 && ih < H_DIM)
                v = *reinterpret_cast<const f4*>(plane + ih * W_DIM + (ow4 << 2));
            a[i] = v;
            // halo from neighbor lanes; ow4 groups align with 32-lane segments
            const float l = __shfl_up(v.w, 1, 32);    // x[.., 4*ow4 - 1]
            const float r = __shfl_down(v.x, 1, 32);  // x[.., 4*ow4 + 4]
            lft[i] = (ow4 == 0)  ? 0.f : l;
            rgt[i] = (ow4 == 31) ? 0.f : r;
        }

        float* obase = out + (size_t)bc * (9 * PLANE) + (oh << 7) + (ow4 << 2);
#pragma unroll
        for (int i = 0; i < 3; ++i) {
            const f4 o0 = {lft[i], a[i].x, a[i].y, a[i].z};  // j=0
            const f4 o1 = a[i];                              // j=1
            const f4 o2 = {a[i].y, a[i].z, a[i].w, rgt[i]};  // j=2
            __builtin_nontemporal_store(
                o0, reinterpret_cast<f4*>(obase + (size_t)(3 * i + 0) * PLANE));
            __builtin_nontemporal_store(
                o1, reinterpret_cast<f4*>(obase + (size_t)(3 * i + 1) * PLANE));
            __builtin_nontemporal_store(
                o2, reinterpret_cast<f4*>(obase + (size_t)(3 * i + 2) * PLANE));
        }
    }
}

extern "C" void kernel_launch(void* const* d_in, const int* in_sizes, int n_in,
                              void* d_out, int out_size, void* d_ws, size_t ws_size,
                              hipStream_t stream) {
    const float* x = (const float*)d_in[0];
    float* out = (float*)d_out;

    // work items = BC * OH * OW4 = 1024 * 128 * 32 = 4,194,304
    const int total = (out_size / 9) / 4;
    const int block = 256;
    const int grid  = 2048;  // 8 blocks/CU; grid-stride covers 8 iterations
    unfold9_nt_kernel<<<grid, block, 0, stream>>>(x, out, total);
}